// Round 1
// baseline (6879.041 us; speedup 1.0000x reference)
//
#include <hip/hip_runtime.h>
#include <math.h>

// Problem constants (from reference): B=4, T=32, N=32, F=16, GH=64, LH=128
#define T_STEPS 32
#define NNODES  32
#define FEAT    16
#define GHID    64
#define LSTM_IN 2048   // N*GH
#define LSTM_H  4096   // N*LH
#define GATES   16384  // 4*LSTM_H
#define BT      128    // B*T

__device__ __forceinline__ float sigmoidf_(float x) { return 1.0f / (1.0f + __expf(-x)); }

// ---------------------------------------------------------------- zero init
__global__ void zero_f(float* p, int n) {
    int i = blockIdx.x * 256 + threadIdx.x;
    if (i < n) p[i] = 0.0f;
}

// ------------------------------------------------- dense normalized adjacency
// A[dst][src] = dinv[src]*dinv[dst], accumulated over E edges + N self loops.
__global__ void build_adj(const int* __restrict__ ei, int E, float* __restrict__ A) {
    __shared__ float As[NNODES * NNODES];
    __shared__ int   deg[NNODES];
    __shared__ float dinv[NNODES];
    int tid = threadIdx.x;
    if (tid < NNODES) deg[tid] = 1;  // self loop contributes 1 to deg
    for (int i = tid; i < NNODES * NNODES; i += 256) As[i] = 0.0f;
    __syncthreads();
    for (int e = tid; e < E; e += 256) {
        int d = ei[E + e];
        atomicAdd(&deg[d], 1);
    }
    __syncthreads();
    if (tid < NNODES) dinv[tid] = rsqrtf((float)deg[tid]);
    __syncthreads();
    for (int e = tid; e < E; e += 256) {
        int s = ei[e], d = ei[E + e];
        atomicAdd(&As[d * NNODES + s], dinv[s] * dinv[d]);
    }
    if (tid < NNODES) atomicAdd(&As[tid * NNODES + tid], dinv[tid] * dinv[tid]);
    __syncthreads();
    for (int i = tid; i < NNODES * NNODES; i += 256) A[i] = As[i];
}

// ------------------------------------------- LN + GCN1 + GCN2, one block/(b,t)
__global__ __launch_bounds__(256) void gcn2_kernel(
    const float* __restrict__ x, const float* __restrict__ ln_g, const float* __restrict__ ln_b,
    const float* __restrict__ W1, const float* __restrict__ b1,
    const float* __restrict__ W2, const float* __restrict__ b2,
    const float* __restrict__ A, float* __restrict__ seq)
{
    __shared__ float As[NNODES * NNODES];   // 1024
    __shared__ float w1[FEAT * GHID];       // 1024
    __shared__ float w2[GHID * GHID];       // 4096
    __shared__ float xln[NNODES * FEAT];    // 512
    __shared__ float h1[NNODES * GHID];     // 2048
    __shared__ float g1[NNODES * GHID];     // 2048
    __shared__ float h2[NNODES * GHID];     // 2048

    int tid = threadIdx.x;
    int bt = blockIdx.x;
    const float* xb = x + (size_t)bt * NNODES * FEAT;

    for (int i = tid; i < 1024; i += 256) As[i] = A[i];
    for (int i = tid; i < FEAT * GHID; i += 256) w1[i] = W1[i];
    for (int i = tid; i < GHID * GHID; i += 256) w2[i] = W2[i];
    for (int i = tid; i < NNODES * FEAT; i += 256) xln[i] = xb[i];
    __syncthreads();

    if (tid < NNODES) {
        float mu = 0.0f;
        for (int f = 0; f < FEAT; ++f) mu += xln[tid * FEAT + f];
        mu *= (1.0f / FEAT);
        float var = 0.0f;
        for (int f = 0; f < FEAT; ++f) {
            float d = xln[tid * FEAT + f] - mu;
            var += d * d;
        }
        var *= (1.0f / FEAT);
        float r = rsqrtf(var + 1e-5f);
        for (int f = 0; f < FEAT; ++f)
            xln[tid * FEAT + f] = (xln[tid * FEAT + f] - mu) * r * ln_g[f] + ln_b[f];
    }
    __syncthreads();

    // h1 = xln @ W1
    for (int idx = tid; idx < NNODES * GHID; idx += 256) {
        int n = idx >> 6, j = idx & 63;
        float s = 0.0f;
        #pragma unroll
        for (int f = 0; f < FEAT; ++f) s += xln[n * FEAT + f] * w1[f * GHID + j];
        h1[idx] = s;
    }
    __syncthreads();
    // g1 = A @ h1 + b1
    for (int idx = tid; idx < NNODES * GHID; idx += 256) {
        int n = idx >> 6, j = idx & 63;
        float s = b1[j];
        #pragma unroll 8
        for (int m = 0; m < NNODES; ++m) s += As[n * NNODES + m] * h1[m * GHID + j];
        g1[idx] = s;
    }
    __syncthreads();
    // h2 = g1 @ W2
    for (int idx = tid; idx < NNODES * GHID; idx += 256) {
        int n = idx >> 6, j = idx & 63;
        float s = 0.0f;
        #pragma unroll 8
        for (int k = 0; k < GHID; ++k) s += g1[n * GHID + k] * w2[k * GHID + j];
        h2[idx] = s;
    }
    __syncthreads();
    // out = A @ h2 + b2  -> seq[bt, n*64+j]
    for (int idx = tid; idx < NNODES * GHID; idx += 256) {
        int n = idx >> 6, j = idx & 63;
        float s = b2[j];
        #pragma unroll 8
        for (int m = 0; m < NNODES; ++m) s += As[n * NNODES + m] * h2[m * GHID + j];
        seq[(size_t)bt * LSTM_IN + idx] = s;
    }
}

// ---------------------------------- x_proj = seq @ W_ih^T + (b_ih + b_hh)
// Tiles: 64 bt-rows (blockIdx.y) x 128 g-cols (blockIdx.x). K chunks of 32.
#define SS_STRIDE 68
#define WS_STRIDE 132
__global__ __launch_bounds__(256) void xproj_gemm(
    const float* __restrict__ seq, const float* __restrict__ W_ih,
    const float* __restrict__ b_ih, const float* __restrict__ b_hh,
    float* __restrict__ xproj)
{
    __shared__ float Ss[32 * SS_STRIDE];   // [k][bt]
    __shared__ float Ws[32 * WS_STRIDE];   // [k][g]
    int tid = threadIdx.x;
    int btb = blockIdx.y * 64;
    int gb  = blockIdx.x * 128;
    int bt0 = (tid >> 5) * 8;   // 8 groups of 8 rows
    int g0  = (tid & 31) * 4;   // 32 groups of 4 cols

    float acc[8][4];
    #pragma unroll
    for (int i = 0; i < 8; ++i)
        #pragma unroll
        for (int j = 0; j < 4; ++j) acc[i][j] = 0.0f;

    for (int k0 = 0; k0 < LSTM_IN; k0 += 32) {
        #pragma unroll
        for (int i = 0; i < 8; ++i) {
            int e = tid + i * 256;           // 2048 = 64bt x 32k
            int bt = e >> 5, k = e & 31;
            Ss[k * SS_STRIDE + bt] = seq[(size_t)(btb + bt) * LSTM_IN + k0 + k];
        }
        #pragma unroll
        for (int i = 0; i < 16; ++i) {
            int e = tid + i * 256;           // 4096 = 128g x 32k
            int g = e >> 5, k = e & 31;
            Ws[k * WS_STRIDE + g] = W_ih[(size_t)(gb + g) * LSTM_IN + k0 + k];
        }
        __syncthreads();
        #pragma unroll 8
        for (int k = 0; k < 32; ++k) {
            float4 b4 = *(const float4*)&Ws[k * WS_STRIDE + g0];
            float4 a0 = *(const float4*)&Ss[k * SS_STRIDE + bt0];
            float4 a1 = *(const float4*)&Ss[k * SS_STRIDE + bt0 + 4];
            float a[8] = {a0.x, a0.y, a0.z, a0.w, a1.x, a1.y, a1.z, a1.w};
            #pragma unroll
            for (int i = 0; i < 8; ++i) {
                acc[i][0] += a[i] * b4.x;
                acc[i][1] += a[i] * b4.y;
                acc[i][2] += a[i] * b4.z;
                acc[i][3] += a[i] * b4.w;
            }
        }
        __syncthreads();
    }

    int gcol = gb + g0;
    float4 bias;
    bias.x = b_ih[gcol + 0] + b_hh[gcol + 0];
    bias.y = b_ih[gcol + 1] + b_hh[gcol + 1];
    bias.z = b_ih[gcol + 2] + b_hh[gcol + 2];
    bias.w = b_ih[gcol + 3] + b_hh[gcol + 3];
    #pragma unroll
    for (int i = 0; i < 8; ++i) {
        int row = btb + bt0 + i;
        float4 o;
        o.x = acc[i][0] + bias.x;
        o.y = acc[i][1] + bias.y;
        o.z = acc[i][2] + bias.z;
        o.w = acc[i][3] + bias.w;
        *(float4*)&xproj[(size_t)row * GATES + gcol] = o;
    }
}

// -------------------------------------------------- one LSTM time step
// One wave per h-index j: 4 gate rows x 4 batches. h staged in LDS.
__global__ __launch_bounds__(256) void lstm_step(
    const float* __restrict__ Whh, const float* __restrict__ xproj,
    const float* __restrict__ h_in, float* __restrict__ h_out,
    float* __restrict__ c, int t)
{
    __shared__ float hs[4 * LSTM_H];   // 64 KB
    int tid = threadIdx.x;
    const float4* h4 = (const float4*)h_in;
    float4* hs4 = (float4*)hs;
    #pragma unroll
    for (int i = 0; i < 16; ++i) hs4[tid + i * 256] = h4[tid + i * 256];
    __syncthreads();

    int w = tid >> 6, lane = tid & 63;
    int j = blockIdx.x * 4 + w;

    float acc[4][4];
    #pragma unroll
    for (int g = 0; g < 4; ++g)
        #pragma unroll
        for (int b = 0; b < 4; ++b) acc[g][b] = 0.0f;

    #pragma unroll 1
    for (int gate = 0; gate < 4; ++gate) {
        const float4* Wr = (const float4*)(Whh + (size_t)(gate * LSTM_H + j) * LSTM_H);
        #pragma unroll
        for (int it = 0; it < 16; ++it) {
            float4 wv = Wr[it * 64 + lane];
            int k = (it * 64 + lane) * 4;
            #pragma unroll
            for (int b = 0; b < 4; ++b) {
                const float4 hv = *(const float4*)&hs[b * LSTM_H + k];
                acc[gate][b] += wv.x * hv.x + wv.y * hv.y + wv.z * hv.z + wv.w * hv.w;
            }
        }
    }

    // butterfly reduce across the 64-lane wave
    #pragma unroll
    for (int off = 32; off > 0; off >>= 1) {
        #pragma unroll
        for (int g = 0; g < 4; ++g)
            #pragma unroll
            for (int b = 0; b < 4; ++b)
                acc[g][b] += __shfl_xor(acc[g][b], off, 64);
    }

    if (lane < 4) {
        int b = lane;
        size_t xbase = (size_t)(b * T_STEPS + t) * GATES + j;
        float gi = sigmoidf_(acc[0][b] + xproj[xbase]);
        float gf = sigmoidf_(acc[1][b] + xproj[xbase + LSTM_H]);
        float gg = tanhf(acc[2][b] + xproj[xbase + 2 * LSTM_H]);
        float go = sigmoidf_(acc[3][b] + xproj[xbase + 3 * LSTM_H]);
        float cn = gf * c[b * LSTM_H + j] + gi * gg;
        float hn = go * tanhf(cn);
        c[b * LSTM_H + j] = cn;
        h_out[b * LSTM_H + j] = hn;
    }
}

// -------------------------------------------------- final FC: [4,32,128]@[128]
__global__ void final_fc(const float* __restrict__ h, const float* __restrict__ fcW,
                         const float* __restrict__ fcb, float* __restrict__ out)
{
    int i = threadIdx.x;
    if (i < 128) {
        int b = i >> 5, n = i & 31;
        const float* hp = h + (size_t)b * LSTM_H + n * 128;
        float s = 0.0f;
        #pragma unroll 8
        for (int l = 0; l < 128; ++l) s += hp[l] * fcW[l];
        out[i] = s + fcb[0];
    }
}

extern "C" void kernel_launch(void* const* d_in, const int* in_sizes, int n_in,
                              void* d_out, int out_size, void* d_ws, size_t ws_size,
                              hipStream_t stream)
{
    const float* x    = (const float*)d_in[0];
    const int*   ei   = (const int*)d_in[1];
    const float* ln_g = (const float*)d_in[2];
    const float* ln_b = (const float*)d_in[3];
    const float* W1   = (const float*)d_in[4];
    const float* b1   = (const float*)d_in[5];
    const float* W2   = (const float*)d_in[6];
    const float* b2   = (const float*)d_in[7];
    const float* W_ih = (const float*)d_in[8];
    const float* b_ih = (const float*)d_in[9];
    const float* W_hh = (const float*)d_in[10];
    const float* b_hh = (const float*)d_in[11];
    const float* fcW  = (const float*)d_in[12];
    const float* fcb  = (const float*)d_in[13];
    int E = in_sizes[1] / 2;

    float* ws  = (float*)d_ws;
    float* A   = ws;                    // 1024
    float* seq = A + 1024;              // 128*2048 = 262144
    float* xp  = seq + 262144;          // 128*16384 = 2097152
    float* h0  = xp + 2097152;          // 16384
    float* c   = h0 + 16384;            // 16384
    float* h1  = c + 16384;             // 16384
    // total ~9.2 MB

    zero_f<<<dim3(128), dim3(256), 0, stream>>>(h0, 32768);   // zero h0 + c
    build_adj<<<dim3(1), dim3(256), 0, stream>>>(ei, E, A);
    gcn2_kernel<<<dim3(BT), dim3(256), 0, stream>>>(x, ln_g, ln_b, W1, b1, W2, b2, A, seq);
    xproj_gemm<<<dim3(128, 2), dim3(256), 0, stream>>>(seq, W_ih, b_ih, b_hh, xp);

    for (int t = 0; t < T_STEPS; ++t) {
        const float* hin = (t & 1) ? h1 : h0;
        float* hout      = (t & 1) ? h0 : h1;
        lstm_step<<<dim3(LSTM_H / 4), dim3(256), 0, stream>>>(W_hh, xp, hin, hout, c, t);
    }
    // after t=31 (odd), last h is in h0
    final_fc<<<dim3(1), dim3(128), 0, stream>>>(h0, fcW, fcb, (float*)d_out);
}

// Round 2
// 1359.816 us; speedup vs baseline: 5.0588x; 5.0588x over previous
//
#include <hip/hip_runtime.h>
#include <math.h>

// B=4, T=32, N=32, F=16, GH=64, LH=128
#define T_STEPS 32
#define NNODES  32
#define FEAT    16
#define GHID    64
#define LSTM_IN 2048   // N*GH
#define LSTM_H  4096   // N*LH
#define GATES   16384  // 4*LSTM_H
#define BT      128    // B*T

typedef __attribute__((ext_vector_type(8))) short bhalf8;
typedef __attribute__((ext_vector_type(4))) float floatx4;

__device__ __forceinline__ float sigmoidf_(float x) { return 1.0f / (1.0f + __expf(-x)); }

// fp32 -> bf16 (RNE)
__device__ __forceinline__ unsigned short f2bf(float f) {
    unsigned int u = __float_as_uint(f);
    u += 0x7FFFu + ((u >> 16) & 1u);
    return (unsigned short)(u >> 16);
}
// unpack 2 bf16 from a uint
__device__ __forceinline__ float bf_lo(unsigned int u) { return __uint_as_float(u << 16); }
__device__ __forceinline__ float bf_hi(unsigned int u) { return __uint_as_float(u & 0xFFFF0000u); }

// ---------------------------------------------------------------- zero init
__global__ void zero_f(float* p, int n) {
    int i = blockIdx.x * 256 + threadIdx.x;
    if (i < n) p[i] = 0.0f;
}

// ------------------------------------------------- fp32 -> bf16 bulk convert
__global__ void conv_bf16(const float* __restrict__ src, unsigned short* __restrict__ dst, int n4) {
    int i = blockIdx.x * 256 + threadIdx.x;
    if (i < n4) {
        float4 v = ((const float4*)src)[i];
        ushort4 o;
        o.x = f2bf(v.x); o.y = f2bf(v.y); o.z = f2bf(v.z); o.w = f2bf(v.w);
        ((ushort4*)dst)[i] = o;
    }
}

// ------------------------------------------------- dense normalized adjacency
__global__ void build_adj(const int* __restrict__ ei, int E, float* __restrict__ A) {
    __shared__ float As[NNODES * NNODES];
    __shared__ int   deg[NNODES];
    __shared__ float dinv[NNODES];
    int tid = threadIdx.x;
    if (tid < NNODES) deg[tid] = 1;
    for (int i = tid; i < NNODES * NNODES; i += 256) As[i] = 0.0f;
    __syncthreads();
    for (int e = tid; e < E; e += 256) atomicAdd(&deg[ei[E + e]], 1);
    __syncthreads();
    if (tid < NNODES) dinv[tid] = rsqrtf((float)deg[tid]);
    __syncthreads();
    for (int e = tid; e < E; e += 256) {
        int s = ei[e], d = ei[E + e];
        atomicAdd(&As[d * NNODES + s], dinv[s] * dinv[d]);
    }
    if (tid < NNODES) atomicAdd(&As[tid * NNODES + tid], dinv[tid] * dinv[tid]);
    __syncthreads();
    for (int i = tid; i < NNODES * NNODES; i += 256) A[i] = As[i];
}

// ------------------------------------------- LN + GCN1 + GCN2, one block/(b,t)
__global__ __launch_bounds__(256) void gcn2_kernel(
    const float* __restrict__ x, const float* __restrict__ ln_g, const float* __restrict__ ln_b,
    const float* __restrict__ W1, const float* __restrict__ b1,
    const float* __restrict__ W2, const float* __restrict__ b2,
    const float* __restrict__ A, float* __restrict__ seq)
{
    __shared__ float As[NNODES * NNODES];
    __shared__ float w1[FEAT * GHID];
    __shared__ float w2[GHID * GHID];
    __shared__ float xln[NNODES * FEAT];
    __shared__ float h1[NNODES * GHID];
    __shared__ float g1[NNODES * GHID];
    __shared__ float h2[NNODES * GHID];

    int tid = threadIdx.x;
    int bt = blockIdx.x;
    const float* xb = x + (size_t)bt * NNODES * FEAT;

    for (int i = tid; i < 1024; i += 256) As[i] = A[i];
    for (int i = tid; i < FEAT * GHID; i += 256) w1[i] = W1[i];
    for (int i = tid; i < GHID * GHID; i += 256) w2[i] = W2[i];
    for (int i = tid; i < NNODES * FEAT; i += 256) xln[i] = xb[i];
    __syncthreads();

    if (tid < NNODES) {
        float mu = 0.0f;
        for (int f = 0; f < FEAT; ++f) mu += xln[tid * FEAT + f];
        mu *= (1.0f / FEAT);
        float var = 0.0f;
        for (int f = 0; f < FEAT; ++f) { float d = xln[tid * FEAT + f] - mu; var += d * d; }
        var *= (1.0f / FEAT);
        float r = rsqrtf(var + 1e-5f);
        for (int f = 0; f < FEAT; ++f)
            xln[tid * FEAT + f] = (xln[tid * FEAT + f] - mu) * r * ln_g[f] + ln_b[f];
    }
    __syncthreads();

    for (int idx = tid; idx < NNODES * GHID; idx += 256) {
        int n = idx >> 6, j = idx & 63;
        float s = 0.0f;
        #pragma unroll
        for (int f = 0; f < FEAT; ++f) s += xln[n * FEAT + f] * w1[f * GHID + j];
        h1[idx] = s;
    }
    __syncthreads();
    for (int idx = tid; idx < NNODES * GHID; idx += 256) {
        int n = idx >> 6, j = idx & 63;
        float s = b1[j];
        #pragma unroll 8
        for (int m = 0; m < NNODES; ++m) s += As[n * NNODES + m] * h1[m * GHID + j];
        g1[idx] = s;
    }
    __syncthreads();
    for (int idx = tid; idx < NNODES * GHID; idx += 256) {
        int n = idx >> 6, j = idx & 63;
        float s = 0.0f;
        #pragma unroll 8
        for (int k = 0; k < GHID; ++k) s += g1[n * GHID + k] * w2[k * GHID + j];
        h2[idx] = s;
    }
    __syncthreads();
    for (int idx = tid; idx < NNODES * GHID; idx += 256) {
        int n = idx >> 6, j = idx & 63;
        float s = b2[j];
        #pragma unroll 8
        for (int m = 0; m < NNODES; ++m) s += As[n * NNODES + m] * h2[m * GHID + j];
        seq[(size_t)bt * LSTM_IN + idx] = s;
    }
}

// ---------------------------------- x_proj partials via MFMA, fused fp32->bf16
// Wave task: (ntile, kc). ntile covers 16 g-cols, kc covers K chunk of 512.
// D tile: M=128 (all bt rows, 8 sub-tiles) x N=16.
__global__ __launch_bounds__(256) void xproj_mfma(
    const float* __restrict__ seq, const float* __restrict__ W_ih,
    float* __restrict__ xpart)
{
    int lane = threadIdx.x & 63;
    int wid = blockIdx.x * 4 + (threadIdx.x >> 6);  // 0..4095
    int ntile = wid >> 2;                            // 0..1023
    int kc = wid & 3;                                // 0..3
    int n0 = ntile << 4;
    int rr = lane & 15;                              // row-in-frag (A:m, B:n, D:col)
    int kg = lane >> 4;                              // k group 0..3

    floatx4 acc[8];
    #pragma unroll
    for (int mt = 0; mt < 8; ++mt) acc[mt] = (floatx4){0.f, 0.f, 0.f, 0.f};

    for (int ks = 0; ks < 16; ++ks) {
        int k0 = (kc << 9) + (ks << 5) + (kg << 3);
        const float4* wp = (const float4*)(W_ih + (size_t)(n0 + rr) * LSTM_IN + k0);
        float4 w0 = wp[0], w1 = wp[1];
        bhalf8 bf;
        bf[0] = (short)f2bf(w0.x); bf[1] = (short)f2bf(w0.y);
        bf[2] = (short)f2bf(w0.z); bf[3] = (short)f2bf(w0.w);
        bf[4] = (short)f2bf(w1.x); bf[5] = (short)f2bf(w1.y);
        bf[6] = (short)f2bf(w1.z); bf[7] = (short)f2bf(w1.w);
        #pragma unroll
        for (int mt = 0; mt < 8; ++mt) {
            const float4* ap = (const float4*)(seq + (size_t)(mt * 16 + rr) * LSTM_IN + k0);
            float4 a0 = ap[0], a1 = ap[1];
            bhalf8 af;
            af[0] = (short)f2bf(a0.x); af[1] = (short)f2bf(a0.y);
            af[2] = (short)f2bf(a0.z); af[3] = (short)f2bf(a0.w);
            af[4] = (short)f2bf(a1.x); af[5] = (short)f2bf(a1.y);
            af[6] = (short)f2bf(a1.z); af[7] = (short)f2bf(a1.w);
            acc[mt] = __builtin_amdgcn_mfma_f32_16x16x32_bf16(af, bf, acc[mt], 0, 0, 0);
        }
    }
    // D mapping: col = lane&15 (g), row = kg*4 + i (bt within sub-tile)
    float* xo = xpart + (size_t)kc * (BT * GATES);
    #pragma unroll
    for (int mt = 0; mt < 8; ++mt) {
        #pragma unroll
        for (int i = 0; i < 4; ++i) {
            int row = mt * 16 + kg * 4 + i;
            xo[(size_t)row * GATES + n0 + rr] = acc[mt][i];
        }
    }
}

// -------------------------------- combine 4 K-partials + bias -> xp
__global__ void combine_xp(const float* __restrict__ xpart,
                           const float* __restrict__ b_ih, const float* __restrict__ b_hh,
                           float* __restrict__ xp)
{
    int i = blockIdx.x * 256 + threadIdx.x;      // float4 index, total 524288
    const float4* p0 = (const float4*)xpart;
    const float4* p1 = p0 + (BT * GATES / 4);
    const float4* p2 = p1 + (BT * GATES / 4);
    const float4* p3 = p2 + (BT * GATES / 4);
    float4 a = p0[i], b = p1[i], c = p2[i], d = p3[i];
    int col = (i & (GATES / 4 - 1)) << 2;
    float4 o;
    o.x = a.x + b.x + c.x + d.x + b_ih[col + 0] + b_hh[col + 0];
    o.y = a.y + b.y + c.y + d.y + b_ih[col + 1] + b_hh[col + 1];
    o.z = a.z + b.z + c.z + d.z + b_ih[col + 2] + b_hh[col + 2];
    o.w = a.w + b.w + c.w + d.w + b_ih[col + 3] + b_hh[col + 3];
    ((float4*)xp)[i] = o;
}

// -------------------------------------------------- one LSTM time step (bf16)
// One wave per j: 4 gates x 4 batches. Weights bf16 (L3-resident), h bf16 planar [b][4096].
__global__ __launch_bounds__(256) void lstm_step_bf16(
    const unsigned short* __restrict__ Wbf, const float* __restrict__ xp,
    const unsigned short* __restrict__ hin, unsigned short* __restrict__ hout,
    float* __restrict__ hf32, float* __restrict__ c, int t)
{
    int lane = threadIdx.x & 63;
    int w = threadIdx.x >> 6;
    int j = blockIdx.x * 4 + w;

    float acc[4][4];
    #pragma unroll
    for (int g = 0; g < 4; ++g)
        #pragma unroll
        for (int b = 0; b < 4; ++b) acc[g][b] = 0.0f;

    #pragma unroll 1
    for (int ks = 0; ks < 8; ++ks) {
        int kb = ks * 512 + lane * 8;   // element index into 4096
        // h chunk: 4 batches x 8 k (bf16)
        float h8[4][8];
        #pragma unroll
        for (int b = 0; b < 4; ++b) {
            uint4 hv = *(const uint4*)(hin + b * LSTM_H + kb);
            h8[b][0] = bf_lo(hv.x); h8[b][1] = bf_hi(hv.x);
            h8[b][2] = bf_lo(hv.y); h8[b][3] = bf_hi(hv.y);
            h8[b][4] = bf_lo(hv.z); h8[b][5] = bf_hi(hv.z);
            h8[b][6] = bf_lo(hv.w); h8[b][7] = bf_hi(hv.w);
        }
        #pragma unroll
        for (int g = 0; g < 4; ++g) {
            uint4 wv = *(const uint4*)(Wbf + ((size_t)(g * LSTM_H + j) << 12) + kb);
            float w8[8];
            w8[0] = bf_lo(wv.x); w8[1] = bf_hi(wv.x);
            w8[2] = bf_lo(wv.y); w8[3] = bf_hi(wv.y);
            w8[4] = bf_lo(wv.z); w8[5] = bf_hi(wv.z);
            w8[6] = bf_lo(wv.w); w8[7] = bf_hi(wv.w);
            #pragma unroll
            for (int k = 0; k < 8; ++k) {
                acc[g][0] += w8[k] * h8[0][k];
                acc[g][1] += w8[k] * h8[1][k];
                acc[g][2] += w8[k] * h8[2][k];
                acc[g][3] += w8[k] * h8[3][k];
            }
        }
    }

    #pragma unroll
    for (int off = 32; off > 0; off >>= 1) {
        #pragma unroll
        for (int g = 0; g < 4; ++g)
            #pragma unroll
            for (int b = 0; b < 4; ++b)
                acc[g][b] += __shfl_xor(acc[g][b], off, 64);
    }

    if (lane < 4) {
        int b = lane;
        size_t xb = ((size_t)(b * T_STEPS + t)) * GATES + j;
        float gi = sigmoidf_(acc[0][b] + xp[xb]);
        float gf = sigmoidf_(acc[1][b] + xp[xb + LSTM_H]);
        float gg = tanhf   (acc[2][b] + xp[xb + 2 * LSTM_H]);
        float go = sigmoidf_(acc[3][b] + xp[xb + 3 * LSTM_H]);
        float cn = gf * c[b * LSTM_H + j] + gi * gg;
        float hn = go * tanhf(cn);
        c[b * LSTM_H + j] = cn;
        hf32[b * LSTM_H + j] = hn;
        hout[b * LSTM_H + j] = f2bf(hn);
    }
}

// -------------------------------------------------- final FC
__global__ void final_fc(const float* __restrict__ h, const float* __restrict__ fcW,
                         const float* __restrict__ fcb, float* __restrict__ out)
{
    int i = threadIdx.x;
    if (i < 128) {
        int b = i >> 5, n = i & 31;
        const float* hp = h + (size_t)b * LSTM_H + n * 128;
        float s = 0.0f;
        #pragma unroll 8
        for (int l = 0; l < 128; ++l) s += hp[l] * fcW[l];
        out[i] = s + fcb[0];
    }
}

extern "C" void kernel_launch(void* const* d_in, const int* in_sizes, int n_in,
                              void* d_out, int out_size, void* d_ws, size_t ws_size,
                              hipStream_t stream)
{
    const float* x    = (const float*)d_in[0];
    const int*   ei   = (const int*)d_in[1];
    const float* ln_g = (const float*)d_in[2];
    const float* ln_b = (const float*)d_in[3];
    const float* W1   = (const float*)d_in[4];
    const float* b1   = (const float*)d_in[5];
    const float* W2   = (const float*)d_in[6];
    const float* b2   = (const float*)d_in[7];
    const float* W_ih = (const float*)d_in[8];
    const float* b_ih = (const float*)d_in[9];
    const float* W_hh = (const float*)d_in[10];
    const float* b_hh = (const float*)d_in[11];
    const float* fcW  = (const float*)d_in[12];
    const float* fcb  = (const float*)d_in[13];
    int E = in_sizes[1] / 2;

    float* ws    = (float*)d_ws;
    float* A     = ws;                         // 1024
    float* seq   = A + 1024;                   // 262144
    float* xp    = seq + 262144;               // 2097152
    float* xpart = xp + 2097152;               // 4*2097152 = 8388608
    float* c     = xpart + 8388608;            // 16384
    float* hbf0f = c + 16384;                  // 8192  (ushort[16384])
    float* hbf1f = hbf0f + 8192;               // 8192
    float* hf32  = hbf1f + 8192;               // 16384
    float* WbfF  = hf32 + 16384;               // 33554432 (ushort[67108864])
    unsigned short* hbf0 = (unsigned short*)hbf0f;
    unsigned short* hbf1 = (unsigned short*)hbf1f;
    unsigned short* Wbf  = (unsigned short*)WbfF;
    // total ~177.4 MB

    // zero c (16384 f) + hbf0 (8192 f-equivalent) — contiguous
    zero_f<<<dim3(96), dim3(256), 0, stream>>>(c, 24576);
    build_adj<<<dim3(1), dim3(256), 0, stream>>>(ei, E, A);
    gcn2_kernel<<<dim3(BT), dim3(256), 0, stream>>>(x, ln_g, ln_b, W1, b1, W2, b2, A, seq);
    conv_bf16<<<dim3(65536), dim3(256), 0, stream>>>(W_hh, Wbf, GATES * LSTM_H / 4);
    xproj_mfma<<<dim3(1024), dim3(256), 0, stream>>>(seq, W_ih, xpart);
    combine_xp<<<dim3(2048), dim3(256), 0, stream>>>(xpart, b_ih, b_hh, xp);

    for (int t = 0; t < T_STEPS; ++t) {
        const unsigned short* hin = (t & 1) ? hbf1 : hbf0;
        unsigned short* hout      = (t & 1) ? hbf0 : hbf1;
        lstm_step_bf16<<<dim3(LSTM_H / 4), dim3(256), 0, stream>>>(Wbf, xp, hin, hout, hf32, c, t);
    }
    final_fc<<<dim3(1), dim3(128), 0, stream>>>(hf32, fcW, fcb, (float*)d_out);
}